// Round 2
// baseline (250.028 us; speedup 1.0000x reference)
//
#include <hip/hip_runtime.h>
#include <hip/hip_bf16.h>
#include <math.h>

// Problem: B=4, N=4096, C=128 single-head attention with fused qkv linear.
// I/O dtype: float32 (per reference). Internally bf16 MFMA (tolerance is
// 2% of max — bf16-grade).
//   k0: W_fc -> WfcT [384][128] bf16, W_out -> WoT [128][128] bf16
//   k1: qkv = x @ W_fc + b_fc; writes Q (pre-scaled by log2e/(sqrt(C)*scale)),
//       K row-major, V TRANSPOSED [B][128][N] -- all bf16 in ws.
//   k2: flash attention, BM=64 BN=64, 4 waves, online softmax in exp2 domain.
//   k3: out = O @ W_out + b_out -> float32 d_out.

typedef __attribute__((ext_vector_type(8))) short bf16x8;
typedef __attribute__((ext_vector_type(4))) short bf16x4;
typedef __attribute__((ext_vector_type(4))) float f32x4;

static __device__ __forceinline__ short f2bf(float f) {
    union { float f; unsigned int u; } c; c.f = f;
    unsigned int u = c.u;
    unsigned int r = (u + 0x7FFFu + ((u >> 16) & 1u)) >> 16;
    return (short)(r & 0xFFFFu);
}

// ---------------- kernel 0: weight transpose + bf16 cast ----------------
__global__ void transpose_w(const float* __restrict__ Wfc, const float* __restrict__ Wout,
                            short* __restrict__ WfcT, short* __restrict__ WoT) {
    int id = blockIdx.x * 256 + threadIdx.x;
    if (id < 384 * 128) {
        int n = id >> 7, k = id & 127;
        WfcT[id] = f2bf(Wfc[k * 384 + n]);
    } else {
        int id2 = id - 384 * 128;
        if (id2 < 128 * 128) {
            int n = id2 >> 7, k = id2 & 127;
            WoT[id2] = f2bf(Wout[k * 128 + n]);
        }
    }
}

// ---------------- kernel 1: qkv GEMM ----------------
// grid (256, 3): blockIdx.x = 64-row block; blockIdx.y selects Q / K / V 128-col chunk.
__global__ __launch_bounds__(256) void qkv_kernel(
    const float* __restrict__ x,      // [16384][128] f32
    const short* __restrict__ WfcT,   // [384][128] bf16
    const float* __restrict__ bfc,    // [384] f32
    const float* __restrict__ scale,  // [1] f32
    short* __restrict__ Qs, short* __restrict__ Kb, short* __restrict__ VT) {
    __shared__ short Xs[64][136];     // +8 pad: fragment reads 2-way banked (free)
    __shared__ short Ws[128][136];

    const int t = threadIdx.x;
    const int rb = blockIdx.x;
    const int cb = blockIdx.y;
    const int lane = t & 63, w = t >> 6;
    const int m16 = lane & 15, quad = lane >> 4;

    {
        int row = t >> 4;
        int col = (t & 15) * 8;
        for (int p = 0; p < 4; ++p) {
            int r = p * 16 + row;
            const float* src = &x[(rb * 64 + r) * 128 + col];
            float4 f0 = *(const float4*)&src[0];
            float4 f1 = *(const float4*)&src[4];
            bf16x8 v;
            v[0] = f2bf(f0.x); v[1] = f2bf(f0.y); v[2] = f2bf(f0.z); v[3] = f2bf(f0.w);
            v[4] = f2bf(f1.x); v[5] = f2bf(f1.y); v[6] = f2bf(f1.z); v[7] = f2bf(f1.w);
            *(bf16x8*)&Xs[r][col] = v;
        }
        for (int p = 0; p < 8; ++p) {
            int r = p * 16 + row;
            *(uint4*)&Ws[r][col] = *(const uint4*)&WfcT[(cb * 128 + r) * 128 + col];
        }
    }
    __syncthreads();

    f32x4 acc[8];
    for (int i = 0; i < 8; ++i)
        for (int j = 0; j < 4; ++j) acc[i][j] = 0.0f;

    for (int kc = 0; kc < 4; ++kc) {
        bf16x8 a = *(const bf16x8*)&Xs[w * 16 + m16][kc * 32 + quad * 8];
        for (int ct = 0; ct < 8; ++ct) {
            bf16x8 b = *(const bf16x8*)&Ws[ct * 16 + m16][kc * 32 + quad * 8];
            acc[ct] = __builtin_amdgcn_mfma_f32_16x16x32_bf16(a, b, acc[ct], 0, 0, 0);
        }
    }

    // sfac folds 1/sqrt(C), 1/scale, AND log2(e) so softmax uses exp2 directly.
    float sfac = 1.44269504088896f / (sqrtf(128.0f) * scale[0]);

    const int rbase = rb * 64 + w * 16 + quad * 4;  // multiple of 4
    for (int ct = 0; ct < 8; ++ct) {
        int c = cb * 128 + ct * 16 + m16;  // 0..383
        float bias = bfc[c];
        if (cb == 0) {
            for (int r = 0; r < 4; ++r)
                Qs[(rbase + r) * 128 + c] = f2bf((acc[ct][r] + bias) * sfac);
        } else if (cb == 1) {
            for (int r = 0; r < 4; ++r)
                Kb[(rbase + r) * 128 + (c - 128)] = f2bf(acc[ct][r] + bias);
        } else {
            int cc = c - 256;
            bf16x4 tv;
            for (int r = 0; r < 4; ++r) tv[r] = f2bf(acc[ct][r] + bias);
            int b_ = rbase >> 12;      // batch
            int nn = rbase & 4095;     // pos in batch (mult of 4; rows stay in batch)
            *(bf16x4*)&VT[(b_ * 128 + cc) * 4096 + nn] = tv;
        }
    }
}

// ---------------- kernel 2: flash attention ----------------
// grid 256 = 4 batches x 64 q-tiles. batch = blk & 3 pins one batch per XCD.
__global__ __launch_bounds__(256) void flash_kernel(
    const short* __restrict__ Qs, const short* __restrict__ Kb,
    const short* __restrict__ VT, short* __restrict__ O) {
    __shared__ short Kst[64][136];   // K tile [BN][C+8]
    __shared__ short VTs[128][72];   // V^T tile [C][BN+8]
    __shared__ short Ps[64][72];     // P tile  [BM][BN+8] (wave-local rows)

    const int t = threadIdx.x;
    const int lane = t & 63, w = t >> 6;
    const int m16 = lane & 15, quad = lane >> 4;
    const int batch = blockIdx.x & 3;
    const int qt = blockIdx.x >> 2;

    // Q fragments: fixed for whole kernel, keep in registers.
    bf16x8 qf[4];
    {
        const short* qbase = Qs + (batch * 4096 + qt * 64 + w * 16 + m16) * 128;
        for (int kc = 0; kc < 4; ++kc)
            qf[kc] = *(const bf16x8*)&qbase[kc * 32 + quad * 8];
    }

    f32x4 acc_o[8];
    for (int i = 0; i < 8; ++i)
        for (int j = 0; j < 4; ++j) acc_o[i][j] = 0.0f;
    float mrow[4], lrow[4];
    for (int r = 0; r < 4; ++r) { mrow[r] = -1e30f; lrow[r] = 0.0f; }

    const int srow = t >> 4;          // staging row 0..15
    const int col8 = (t & 15) * 8;
    const int col4 = (t & 15) * 4;
    const short* kbaseg = Kb + batch * 4096 * 128;
    const short* vbaseg = VT + batch * 128 * 4096;

    uint4 kr[4];
    uint2 vr[8];
    // prefetch tile 0
    for (int p = 0; p < 4; ++p)
        kr[p] = *(const uint4*)&kbaseg[(p * 16 + srow) * 128 + col8];
    for (int p = 0; p < 8; ++p)
        vr[p] = *(const uint2*)&vbaseg[(p * 16 + srow) * 4096 + col4];

    for (int kt = 0; kt < 64; ++kt) {
        __syncthreads();  // previous tile's LDS reads done
        for (int p = 0; p < 4; ++p) *(uint4*)&Kst[p * 16 + srow][col8] = kr[p];
        for (int p = 0; p < 8; ++p) *(uint2*)&VTs[p * 16 + srow][col4] = vr[p];
        __syncthreads();  // tile visible

        if (kt + 1 < 64) {  // register prefetch of next tile overlaps compute
            int kvb = (kt + 1) * 64;
            for (int p = 0; p < 4; ++p)
                kr[p] = *(const uint4*)&kbaseg[(kvb + p * 16 + srow) * 128 + col8];
            for (int p = 0; p < 8; ++p)
                vr[p] = *(const uint2*)&vbaseg[(p * 16 + srow) * 4096 + kvb + col4];
        }

        // S = Q K^T  (16 MFMAs)
        f32x4 s[4];
        for (int i = 0; i < 4; ++i)
            for (int j = 0; j < 4; ++j) s[i][j] = 0.0f;
        for (int kc = 0; kc < 4; ++kc) {
            bf16x8 a = qf[kc];
            for (int ct = 0; ct < 4; ++ct) {
                bf16x8 b = *(const bf16x8*)&Kst[ct * 16 + m16][kc * 32 + quad * 8];
                s[ct] = __builtin_amdgcn_mfma_f32_16x16x32_bf16(a, b, s[ct], 0, 0, 0);
            }
        }

        // online softmax (logits already in log2 domain)
        for (int r = 0; r < 4; ++r) {
            float mx = s[0][r];
            for (int ct = 1; ct < 4; ++ct) mx = fmaxf(mx, s[ct][r]);
            for (int off = 1; off < 16; off <<= 1) mx = fmaxf(mx, __shfl_xor(mx, off, 64));
            float mnew = fmaxf(mrow[r], mx);
            float alpha = __builtin_amdgcn_exp2f(mrow[r] - mnew);
            mrow[r] = mnew;
            float rs = 0.0f;
            short pb[4];
            for (int ct = 0; ct < 4; ++ct) {
                float p = __builtin_amdgcn_exp2f(s[ct][r] - mnew);
                rs += p;
                pb[ct] = f2bf(p);
            }
            for (int off = 1; off < 16; off <<= 1) rs += __shfl_xor(rs, off, 64);
            lrow[r] = lrow[r] * alpha + rs;
            for (int ct = 0; ct < 4; ++ct)
                Ps[w * 16 + quad * 4 + r][ct * 16 + m16] = pb[ct];
            for (int ot = 0; ot < 8; ++ot) acc_o[ot][r] *= alpha;
        }

        // O += P V  (16 MFMAs). Wave reads only its own P rows -> no barrier.
        for (int kc2 = 0; kc2 < 2; ++kc2) {
            bf16x8 a2 = *(const bf16x8*)&Ps[w * 16 + m16][kc2 * 32 + quad * 8];
            for (int ot = 0; ot < 8; ++ot) {
                bf16x8 b2 = *(const bf16x8*)&VTs[ot * 16 + m16][kc2 * 32 + quad * 8];
                acc_o[ot] = __builtin_amdgcn_mfma_f32_16x16x32_bf16(a2, b2, acc_o[ot], 0, 0, 0);
            }
        }
    }

    float rl[4];
    for (int r = 0; r < 4; ++r) rl[r] = 1.0f / lrow[r];
    const int rowb = batch * 4096 + qt * 64 + w * 16 + quad * 4;
    for (int ot = 0; ot < 8; ++ot)
        for (int r = 0; r < 4; ++r)
            O[(rowb + r) * 128 + ot * 16 + m16] = f2bf(acc_o[ot][r] * rl[r]);
}

// ---------------- kernel 3: out projection (f32 output) ----------------
__global__ __launch_bounds__(256) void proj_kernel(
    const short* __restrict__ O, const short* __restrict__ WoT,
    const float* __restrict__ bout, float* __restrict__ out) {
    __shared__ short Os[64][136];
    __shared__ short Ws[128][136];
    const int t = threadIdx.x;
    const int rb = blockIdx.x;
    const int lane = t & 63, w = t >> 6;
    const int m16 = lane & 15, quad = lane >> 4;
    {
        int row = t >> 4, col = (t & 15) * 8;
        for (int p = 0; p < 4; ++p)
            *(uint4*)&Os[p * 16 + row][col] = *(const uint4*)&O[(rb * 64 + p * 16 + row) * 128 + col];
        for (int p = 0; p < 8; ++p)
            *(uint4*)&Ws[p * 16 + row][col] = *(const uint4*)&WoT[(p * 16 + row) * 128 + col];
    }
    __syncthreads();
    f32x4 acc[8];
    for (int i = 0; i < 8; ++i)
        for (int j = 0; j < 4; ++j) acc[i][j] = 0.0f;
    for (int kc = 0; kc < 4; ++kc) {
        bf16x8 a = *(const bf16x8*)&Os[w * 16 + m16][kc * 32 + quad * 8];
        for (int ct = 0; ct < 8; ++ct) {
            bf16x8 b = *(const bf16x8*)&Ws[ct * 16 + m16][kc * 32 + quad * 8];
            acc[ct] = __builtin_amdgcn_mfma_f32_16x16x32_bf16(a, b, acc[ct], 0, 0, 0);
        }
    }
    for (int ct = 0; ct < 8; ++ct) {
        int c = ct * 16 + m16;
        float bias = bout[c];
        for (int r = 0; r < 4; ++r)
            out[(rb * 64 + w * 16 + quad * 4 + r) * 128 + c] = acc[ct][r] + bias;
    }
}

extern "C" void kernel_launch(void* const* d_in, const int* in_sizes, int n_in,
                              void* d_out, int out_size, void* d_ws, size_t ws_size,
                              hipStream_t stream) {
    const float* x     = (const float*)d_in[0];
    const float* Wfc   = (const float*)d_in[1];
    const float* bfc   = (const float*)d_in[2];
    const float* Wout  = (const float*)d_in[3];
    const float* bout  = (const float*)d_in[4];
    const float* scale = (const float*)d_in[5];
    float* out = (float*)d_out;

    char* ws = (char*)d_ws;
    short* WfcT = (short*)(ws);                              // 384*128*2   = 96 KiB
    short* WoT  = (short*)(ws + 98304);                      // 128*128*2   = 32 KiB
    short* Qs   = (short*)(ws + 131072);                     // 16384*128*2 = 4 MiB
    short* Kb   = (short*)(ws + 131072 + 4194304);           // 4 MiB
    short* VT   = (short*)(ws + 131072 + 2 * 4194304);       // 4 MiB  [B][128][4096]
    short* Obuf = (short*)(ws + 131072 + 3 * 4194304);       // 4 MiB
    // total ws use: ~16.2 MiB

    hipLaunchKernelGGL(transpose_w, dim3(256), dim3(256), 0, stream, Wfc, Wout, WfcT, WoT);
    hipLaunchKernelGGL(qkv_kernel, dim3(256, 3), dim3(256), 0, stream, x, WfcT, bfc, scale, Qs, Kb, VT);
    hipLaunchKernelGGL(flash_kernel, dim3(256), dim3(256), 0, stream, Qs, Kb, VT, Obuf);
    hipLaunchKernelGGL(proj_kernel, dim3(256), dim3(256), 0, stream, Obuf, WoT, bout, out);
}